// Round 2
// baseline (469056.982 us; speedup 1.0000x reference)
//
#include <hip/hip_runtime.h>

typedef unsigned int u32;
typedef unsigned short u16;
typedef unsigned long long u64;
typedef __attribute__((ext_vector_type(8))) short bf16x8;
typedef __attribute__((ext_vector_type(4))) float f32x4;
typedef __attribute__((ext_vector_type(4))) unsigned int u32x4;

#define MFMA16(a, b, c) __builtin_amdgcn_mfma_f32_16x16x32_bf16((a), (b), (c), 0, 0, 0)

__device__ __forceinline__ float bf2f(u16 h) {
  union { u32 u; float f; } x; x.u = ((u32)h) << 16; return x.f;
}
__device__ __forceinline__ u16 f2bf(float f) {
  union { float f; u32 u; } x; x.f = f;
  u32 r = (x.u + 0x7FFFu + ((x.u >> 16) & 1u)) >> 16;
  return (u16)r;
}
__device__ __forceinline__ float sigm(float x) { return 1.0f / (1.0f + __expf(-x)); }
__device__ __forceinline__ float tanh_(float x) {
  float e = __expf(2.0f * x);
  return 1.0f - 2.0f / (e + 1.0f);   // safe at +/-inf
}

// ---- same-XCD fast-path primitives: plain stores + sc0 (L1-bypass) loads ----
// Producer stores land in the shared per-XCD L2 (L1 is write-through); consumer
// sc0 loads bypass its L1 and read that same L2. Only valid when the runtime
// rendezvous proves all 8 blocks of a direction share one XCD; otherwise the
// agent-scope-atomic (LLC coherence point) path is used — proven correct.
// Liveness never depends on the fast path: flags are mirrored to the LLC.
__device__ __forceinline__ void ld4x16_sc0(u32x4& d0, u32x4& d1, u32x4& d2, u32x4& d3,
                                           const u32* p0, const u32* p1,
                                           const u32* p2, const u32* p3) {
  asm volatile("global_load_dwordx4 %0, %4, off sc0\n\t"
               "global_load_dwordx4 %1, %5, off sc0\n\t"
               "global_load_dwordx4 %2, %6, off sc0\n\t"
               "global_load_dwordx4 %3, %7, off sc0\n\t"
               "s_waitcnt vmcnt(0)"
               : "=&v"(d0), "=&v"(d1), "=&v"(d2), "=&v"(d3)
               : "v"(p0), "v"(p1), "v"(p2), "v"(p3)
               : "memory");
}
__device__ __forceinline__ bool flags8_sc0(const u32* p, u32 tag) {
  u32x4 a, b;
  asm volatile("global_load_dwordx4 %0, %2, off sc0\n\t"
               "global_load_dwordx4 %1, %2, off offset:16 sc0\n\t"
               "s_waitcnt vmcnt(0)"
               : "=&v"(a), "=&v"(b) : "v"(p) : "memory");
  return (a.x == tag) & (a.y == tag) & (a.z == tag) & (a.w == tag) &
         (b.x == tag) & (b.y == tag) & (b.z == tag) & (b.w == tag);
}
__device__ __forceinline__ bool flags8_agent(const u32* p, u32 tag) {
  const u64 want = (u64)tag * 0x0000000100000001ULL;
  bool ok = true;
#pragma unroll
  for (int i = 0; i < 4; ++i)
    ok &= (__hip_atomic_load((const u64*)p + i, __ATOMIC_RELAXED,
                             __HIP_MEMORY_SCOPE_AGENT) == want);
  return ok;
}
__device__ __forceinline__ u32x4 ld16_agent(const u32* p) {
  u64 a = __hip_atomic_load((const u64*)p, __ATOMIC_RELAXED, __HIP_MEMORY_SCOPE_AGENT);
  u64 b = __hip_atomic_load((const u64*)(p + 2), __ATOMIC_RELAXED, __HIP_MEMORY_SCOPE_AGENT);
  return (u32x4){(u32)a, (u32)(a >> 32), (u32)b, (u32)(b >> 32)};
}

__global__ void sentinelK(float* __restrict__ out) {
  if (threadIdx.x == 0) out[0] = 1.0e6f;   // "workspace too small" marker
}

// ---------------- mask dtype sniffing + pooled masks ----------------
__global__ void modeK(const unsigned char* __restrict__ m, int* __restrict__ mode) {
  if (threadIdx.x == 0) *mode = (m[1] | m[2]) ? 1 : 4;  // 1 = bool bytes, 4 = int32
}

__device__ __forceinline__ bool rawmask(const void* mp, int md, int b, int t) {
  if (md == 1) return ((const unsigned char*)mp)[b * 1696 + t] != 0;
  return ((const int*)mp)[b * 1696 + t] != 0;
}

__global__ __launch_bounds__(256) void maskK(
    const void* __restrict__ m, const int* __restrict__ mode,
    unsigned char* __restrict__ m0, unsigned char* __restrict__ m1,
    unsigned char* __restrict__ m2, unsigned char* __restrict__ m3,
    float* __restrict__ outMask) {
  int idx = blockIdx.x * 256 + threadIdx.x;  // 54272
  int t = idx >> 5, b = idx & 31;
  int md = *mode;
  m0[t * 32 + b] = rawmask(m, md, b, t) ? 1 : 0;
  if (t < 848) {
    bool a = rawmask(m, md, b, 2 * t) && rawmask(m, md, b, 2 * t + 1);
    m1[t * 32 + b] = a ? 1 : 0;
  }
  if (t < 424) {
    bool a = true;
    for (int j = 0; j < 4; ++j) a = a && rawmask(m, md, b, 4 * t + j);
    m2[t * 32 + b] = a ? 1 : 0;
  }
  if (t < 212) {
    bool a = true;
    for (int j = 0; j < 8; ++j) a = a && rawmask(m, md, b, 8 * t + j);
    m3[t * 32 + b] = a ? 1 : 0;
    outMask[b * 212 + t] = a ? 1.0f : 0.0f;
  }
}

// ---------------- positional encoding table (double, matches np.float64 ref) ----
__global__ __launch_bounds__(256) void petK(float* __restrict__ pet) {
  int idx = blockIdx.x * 256 + threadIdx.x;  // 1696*512
  int t = idx >> 9, d = idx & 511;
  double e = (double)((d >> 1) * 2) / 512.0;
  double freq = exp(e * -9.210340371976184);  // 10000^-e
  double ang = (double)t * freq;
  double vv = (d & 1) ? cos(ang) : sin(ang);
  pet[idx] = (float)vv;
}

// ---------------- weight packing: (K,N) fp32 -> (N,K) bf16 ----------------
__global__ __launch_bounds__(256) void packW(const float* __restrict__ src,
                                             u16* __restrict__ dst, int ksh, int N) {
  int idx = blockIdx.x * 256 + threadIdx.x;  // over N*K
  int n = idx >> ksh;
  int k = idx & ((1 << ksh) - 1);
  dst[idx] = f2bf(src[(size_t)k * N + n]);
}

__global__ void biasK(const float* __restrict__ fb, const float* __restrict__ bb,
                      float* __restrict__ dst) {
  int i = blockIdx.x * 256 + threadIdx.x;  // 2048
  dst[i] = (i < 1024) ? fb[i] : bb[i - 1024];
}

// ---------------- chunked mel projection + scale + pet -> xc [2][Cl][32][512] bf16 --
__global__ __launch_bounds__(256) void x0cK(
    const float* __restrict__ inp, const float* __restrict__ dw,
    const float* __restrict__ db, const float* __restrict__ scale,
    const float* __restrict__ pet, u16* __restrict__ xc,
    int t0f, int t0b, int Cl) {
  const int bid = blockIdx.x;          // 2*Cl
  const int d = (bid >= Cl) ? 1 : 0;
  const int lt = bid - d * Cl;
  const int t = (d ? t0b : t0f) + lt;
  __shared__ float xin[32][40];
  for (int i = threadIdx.x; i < 1280; i += 256) {
    int b = i / 40, k = i - b * 40;
    xin[b][k] = inp[((size_t)b * 1696 + t) * 40 + k];
  }
  __syncthreads();
  const float sc = 71.554175279993267f * scale[0];
  for (int dd = threadIdx.x; dd < 512; dd += 256) {
    float w[40];
#pragma unroll
    for (int k = 0; k < 40; ++k) w[k] = dw[k * 512 + dd];
    const float pv = pet[t * 512 + dd];
    const float bv = db[dd];
    u16* out = xc + (((size_t)d * Cl + lt) * 32) * 512 + dd;
    for (int b = 0; b < 32; ++b) {
      float acc = bv;
#pragma unroll
      for (int k = 0; k < 40; ++k) acc += xin[b][k] * w[k];
      out[(size_t)b * 512] = f2bf(acc * sc + pv);
    }
  }
}

// ---------------- one 128x128 GEMM tile (m97-style), used by gemmK and fusedK ------
__device__ __forceinline__ void gemm_tile(
    u16* As, u16* Bs,
    const u16* Af, const u16* Ab, const u16* Wp, const float* bias,
    float* out, int K, int Cl, int bm, int bn, int d, int tid) {
  const u16* A = (d ? Ab : Af) + (size_t)bm * 128 * K;
  const u16* W = Wp + (size_t)d * (size_t)K * 1024 + (size_t)bn * 128 * K;
  const int wv = tid >> 6, L = tid & 63, ln = L & 15, q = L >> 4;
  const int wm = wv & 1, wn = wv >> 1;
  const int srow = L >> 3, scol = (L & 7) * 8;

  f32x4 acc[4][4];
#pragma unroll
  for (int mt = 0; mt < 4; ++mt)
#pragma unroll
    for (int nt = 0; nt < 4; ++nt) acc[mt][nt] = (f32x4){0.f, 0.f, 0.f, 0.f};

  for (int kt = 0; kt < K; kt += 64) {
#pragma unroll
    for (int j = 0; j < 4; ++j) {
      const int rg = (j * 4 + wv) * 8;
      const u16* gA = A + (size_t)(rg + srow) * K + kt + scol;
      const u16* gB = W + (size_t)(rg + srow) * K + kt + scol;
      __builtin_amdgcn_global_load_lds(
          (const __attribute__((address_space(1))) void*)gA,
          (__attribute__((address_space(3))) void*)&As[rg * 64], 16, 0, 0);
      __builtin_amdgcn_global_load_lds(
          (const __attribute__((address_space(1))) void*)gB,
          (__attribute__((address_space(3))) void*)&Bs[rg * 64], 16, 0, 0);
    }
    __syncthreads();
#pragma unroll
    for (int ks = 0; ks < 2; ++ks) {
      bf16x8 a[4], b[4];
#pragma unroll
      for (int mt = 0; mt < 4; ++mt)
        a[mt] = *(const bf16x8*)&As[(wm * 64 + mt * 16 + ln) * 64 + ks * 32 + q * 8];
#pragma unroll
      for (int nt = 0; nt < 4; ++nt)
        b[nt] = *(const bf16x8*)&Bs[(wn * 64 + nt * 16 + ln) * 64 + ks * 32 + q * 8];
#pragma unroll
      for (int mt = 0; mt < 4; ++mt)
#pragma unroll
        for (int nt = 0; nt < 4; ++nt) acc[mt][nt] = MFMA16(a[mt], b[nt], acc[mt][nt]);
    }
    __syncthreads();
  }

  float* outd = out + (size_t)d * Cl * 32768;
#pragma unroll
  for (int nt = 0; nt < 4; ++nt) {
    const int col = bn * 128 + wn * 64 + nt * 16 + ln;
    const float bv = bias[d * 1024 + col];
#pragma unroll
    for (int mt = 0; mt < 4; ++mt) {
      const int row0 = bm * 128 + wm * 64 + mt * 16 + q * 4;
#pragma unroll
      for (int r = 0; r < 4; ++r)
        outd[(size_t)(row0 + r) * 1024 + col] = acc[mt][nt][r] + bv;
    }
  }
}

// ---------------- standalone xz GEMM for chunk 0 of each layer ----------------
__global__ __launch_bounds__(256) void gemmK(
    const u16* __restrict__ Af, const u16* __restrict__ Ab,
    const u16* __restrict__ Wp, const float* __restrict__ bias,
    float* __restrict__ out, int K, int Cl) {
  __shared__ u16 As[128 * 64];
  __shared__ u16 Bs[128 * 64];
  gemm_tile(As, Bs, Af, Ab, Wp, bias, out, K, Cl,
            blockIdx.x, blockIdx.y, blockIdx.z, threadIdx.x);
}

// ---------------- fused: recurrence + next-chunk GEMM + heater ----------------
// Sync role on bids {0,8,...,120}. Per launch, a rendezvous reads HW_REG_XCC_ID
// from every sync block; if a direction's 8 blocks share one XCD, the per-step
// h/flag exchange switches to plain stores + sc0 loads through that XCD's shared
// (coherent) L2 — ~3-4x lower latency than the LLC. Otherwise the proven
// agent-scope-atomic path is used: correctness never depends on placement.
// Hardening: (1) fast-path flags are ALSO mirrored to the LLC via relaxed agent
// atomics (value-identical, fire-and-forget) and the consumer cross-checks that
// view every 1024 spins -> liveness never depends on the sc0 theory; (2) every
// spin has a generous iteration cap so any surprise becomes a wrong answer, not
// a hang; (3) rendezvous timeout poisons the mask so ALL blocks uniformly take
// the slow path (no mixed fast/slow decisions possible).
// Flags: per-dir ring of 16 slots x 8 producer u32 tags; tag = r*16 + epoch+1 is
// launch-unique, so chunk launches never read another launch's flags (cross-chunk
// ordering comes free from stream serialization; poll is skipped at ls==0 —
// same kernel-boundary visibility the baseline already relied on for cbuf/Xnext).
__global__ __launch_bounds__(256) void fusedK(
    const float* __restrict__ xzR,    // [2][Cl][32][1024] f32, chunk r
    const u16* __restrict__ WrP,      // [2][1024][256] bf16 (n,k)
    u16* __restrict__ hbufL,          // [2 dir][2 buf][32][256] bf16
    float* __restrict__ cbufL,        // [2 dir][32][256] f32
    int* __restrict__ flagsL,         // per-layer: ring(256 u32) + chk slots @512
    const unsigned char* __restrict__ msk,  // [T][32]
    u16* __restrict__ Xnext,          // [T/2][32][1024] bf16 (non-final)
    float* __restrict__ outH,         // [32][T][512] f32 (final)
    int T, int Cl, int s0, int isFinal,
    const u16* __restrict__ Af2, const u16* __restrict__ Ab2,
    const u16* __restrict__ WpK, const float* __restrict__ biasL,
    float* __restrict__ xzW, int Kg, int Cg,
    int* __restrict__ doneL, int doneVal, int tagBase) {
  __shared__ u16 As[128 * 64];
  __shared__ u16 Bs[128 * 64];
  __shared__ u16 A_lds[32 * 264];
  __shared__ int hdone;
  __shared__ int sh_fasti;
  const int bid = blockIdx.x;
  const int tid = threadIdx.x;
  const int sub = bid & 7;
  const int grp = bid >> 3;           // 0..31

  if (sub == 0 && grp < 16) {
    // ================= sync role: rid 0..15 =========
    const int rid = grp;
    const int dir = rid >> 3;
    const int wg = rid & 7;
    const int v = tid >> 6;
    const int L = tid & 63;
    const int ln = L & 15;
    const int q = L >> 4;
    const bool low = (L & 8) == 0;
    const int ug = wg * 32 + v * 8 + (L & 7);

    u32* ring = (u32*)flagsL + dir * 128;        // [16 slot][8 wg]

    // --- placement rendezvous (once per launch, per dir; slots zeroed by host) ---
    if (tid == 0) {
      u32 xcc = (u32)__builtin_amdgcn_s_getreg(63508) & 0xFu;  // HW_REG_XCC_ID
      int* chk = flagsL + 512 + 4 * (tagBase >> 4);            // [or0,or1,ct0,ct1]
      __hip_atomic_fetch_or(&chk[dir], (int)(1u << xcc), __ATOMIC_RELAXED,
                            __HIP_MEMORY_SCOPE_AGENT);
      __hip_atomic_fetch_add(&chk[2 + dir], 1, __ATOMIC_RELAXED,
                             __HIP_MEMORY_SCOPE_AGENT);
      int spins = 0;
      while (__hip_atomic_load(&chk[2 + dir], __ATOMIC_RELAXED,
                               __HIP_MEMORY_SCOPE_AGENT) < 8) {
        __builtin_amdgcn_s_sleep(2);
        if (++spins > (1 << 20)) {   // poison -> everyone takes the slow path
          __hip_atomic_fetch_or(&chk[dir], 0x7FFFFFFF, __ATOMIC_RELAXED,
                                __HIP_MEMORY_SCOPE_AGENT);
          break;
        }
      }
      int om = __hip_atomic_load(&chk[dir], __ATOMIC_RELAXED,
                                 __HIP_MEMORY_SCOPE_AGENT);
      sh_fasti = (__popc((u32)om) == 1) ? 1 : 0;
    }
    __syncthreads();
    const bool fastp = (sh_fasti != 0);

    bf16x8 bfr[2][8];
    {
      const u16* wr = WrP + (size_t)dir * 262144;
#pragma unroll
      for (int nt = 0; nt < 2; ++nt) {
        const int n = (nt * 2 + (ln >> 3)) * 256 + ug;  // gate-major column
#pragma unroll
        for (int ks = 0; ks < 8; ++ks)
          bfr[nt][ks] = *(const bf16x8*)(wr + (size_t)n * 256 + ks * 32 + q * 8);
      }
    }
    u16* hb = hbufL + dir * 16384;
    float* cb = cbufL + dir * 8192;

    float cst[2][4];
    if (s0 == 0) {
#pragma unroll
      for (int mt = 0; mt < 2; ++mt)
#pragma unroll
        for (int r = 0; r < 4; ++r) cst[mt][r] = 0.f;
    } else {
#pragma unroll
      for (int mt = 0; mt < 2; ++mt)
#pragma unroll
        for (int r = 0; r < 4; ++r)
          cst[mt][r] = cb[(mt * 16 + q * 4 + r) * 256 + ug];
    }

    for (int s = s0; s < s0 + Cl; ++s) {
      const int t = dir ? (T - 1 - s) : s;
      const int lt = dir ? (s0 + Cl - 1 - s) : (s - s0);
      const int ls = s - s0;

      // prefetch xz + mask — loads in flight during the spin
      float xzv[2][2][4];
      const float* xzt = xzR + ((size_t)dir * Cl + lt) * 32768;
#pragma unroll
      for (int nt = 0; nt < 2; ++nt) {
        const int ncol = (nt * 2 + (ln >> 3)) * 256 + ug;
#pragma unroll
        for (int mt = 0; mt < 2; ++mt)
#pragma unroll
          for (int r = 0; r < 4; ++r)
            xzv[mt][nt][r] = xzt[(size_t)(mt * 16 + q * 4 + r) * 1024 + ncol];
      }
      const u32 mk0 = *(const u32*)&msk[t * 32 + q * 4];
      const u32 mk1 = *(const u32*)&msk[t * 32 + 16 + q * 4];

      // poll previous step's 8 producer tags (skip at chunk start: stream order
      // already guarantees the previous launch's h/c are visible)
      if (ls > 0) {
        if (tid == 0) {
          const u32 tg = (u32)(tagBase + ((ls - 1) >> 4) + 1);
          const u32* fp = ring + ((ls - 1) & 15) * 8;
          if (fastp) {
            int spins = 0;
            for (;;) {
              if (flags8_sc0(fp, tg)) break;
              if ((++spins & 1023) == 0) {
                if (flags8_agent(fp, tg)) break;       // LLC backup view
                if (spins > (1 << 21)) break;          // valve: no hangs, ever
              }
              __builtin_amdgcn_s_sleep(1);
            }
          } else {
            int spins = 0;
            for (;;) {
              if (flags8_agent(fp, tg)) break;
              if (++spins > (1 << 21)) break;          // valve
              __builtin_amdgcn_s_sleep(1);
            }
          }
        }
        __syncthreads();
      }

      // stage h(s-1) (buffer (s+1)&1) into LDS — linear, 16B/lane coalesced
      {
        const u32* hsrc = (const u32*)(hb + ((s + 1) & 1) * 8192);
        const int m0 = tid >> 5;
        const int c4 = (tid & 31) * 4;     // u32 col base
        const u32* p0 = hsrc + (m0)*128 + c4;
        const u32* p1 = hsrc + (8 + m0) * 128 + c4;
        const u32* p2 = hsrc + (16 + m0) * 128 + c4;
        const u32* p3 = hsrc + (24 + m0) * 128 + c4;
        u32x4 v0, v1, v2, v3;
        if (fastp) {
          ld4x16_sc0(v0, v1, v2, v3, p0, p1, p2, p3);
        } else {
          v0 = ld16_agent(p0); v1 = ld16_agent(p1);
          v2 = ld16_agent(p2); v3 = ld16_agent(p3);
        }
        const int lb = (tid & 31) * 8;     // u16 col base
        *(u32x4*)&A_lds[(m0)*264 + lb] = v0;
        *(u32x4*)&A_lds[(8 + m0) * 264 + lb] = v1;
        *(u32x4*)&A_lds[(16 + m0) * 264 + lb] = v2;
        *(u32x4*)&A_lds[(24 + m0) * 264 + lb] = v3;
      }
      __syncthreads();

      f32x4 acc[2][2];
#pragma unroll
      for (int mt = 0; mt < 2; ++mt)
#pragma unroll
        for (int nt = 0; nt < 2; ++nt) acc[mt][nt] = (f32x4){0.f, 0.f, 0.f, 0.f};
#pragma unroll
      for (int ks = 0; ks < 8; ++ks) {
        bf16x8 a0 = *(const bf16x8*)&A_lds[ln * 264 + ks * 32 + q * 8];
        bf16x8 a1 = *(const bf16x8*)&A_lds[(16 + ln) * 264 + ks * 32 + q * 8];
        acc[0][0] = MFMA16(a0, bfr[0][ks], acc[0][0]);
        acc[0][1] = MFMA16(a0, bfr[1][ks], acc[0][1]);
        acc[1][0] = MFMA16(a1, bfr[0][ks], acc[1][0]);
        acc[1][1] = MFMA16(a1, bfr[1][ks], acc[1][1]);
      }

      float hsv[2][4];
#pragma unroll
      for (int mt = 0; mt < 2; ++mt) {
        const u32 mkw = mt ? mk1 : mk0;
#pragma unroll
        for (int r = 0; r < 4; ++r) {
          float z0 = acc[mt][0][r] + xzv[mt][0][r];  // i (low half) / f (high half)
          float z1 = acc[mt][1][r] + xzv[mt][1][r];  // g / o
          float z0p = __shfl_xor(z0, 8);
          float z1p = __shfl_xor(z1, 8);
          float iv = low ? z0 : z0p;
          float fv = low ? z0p : z0;
          float gv = low ? z1 : z1p;
          float ov = low ? z1p : z1;
          float cold = cst[mt][r];
          float cn = sigm(fv) * cold + sigm(iv) * tanh_(gv);
          float hn = sigm(ov) * tanh_(cn);
          const int m = mt * 16 + q * 4 + r;
          float hold = bf2f(A_lds[m * 264 + ug]);
          bool mb = ((mkw >> (8 * r)) & 0xffu) != 0;
          cst[mt][r] = mb ? cn : cold;
          float hs = mb ? hn : hold;
          hsv[mt][r] = hs;
        }
      }

      // publish h(s) to buffer (s&1): fast = plain stores into the shared L2,
      // slow = relaxed agent atomics to the coherence point
      {
        u32* hdst = (u32*)(hb + (s & 1) * 8192);
#pragma unroll
        for (int mt = 0; mt < 2; ++mt) {
#pragma unroll
          for (int r = 0; r < 4; ++r) {
            u32 lo = (u32)f2bf(hsv[mt][r]);
            u32 par = (u32)__shfl_xor((int)lo, 1);
            u32 val = lo | (par << 16);
            if (low && ((ln & 1) == 0)) {
              const int m = mt * 16 + q * 4 + r;
              if (fastp)
                hdst[m * 128 + (ug >> 1)] = val;
              else
                __hip_atomic_store(&hdst[m * 128 + (ug >> 1)], val,
                                   __ATOMIC_RELAXED, __HIP_MEMORY_SCOPE_AGENT);
            }
          }
        }
      }

      asm volatile("s_waitcnt vmcnt(0)" ::: "memory");  // this wave's h acked
      __syncthreads();                                   // all waves drained
      if (tid == 0) {
        const u32 tg = (u32)(tagBase + (ls >> 4) + 1);
        u32* fdst = ring + (ls & 15) * 8 + wg;
        if (fastp) {
          asm volatile("global_store_dword %0, %1, off" ::"v"(fdst), "v"(tg)
                       : "memory");
          // LLC mirror (same value; fire-and-forget) — liveness insurance
          __hip_atomic_store(fdst, tg, __ATOMIC_RELAXED, __HIP_MEMORY_SCOPE_AGENT);
        } else {
          __hip_atomic_store(fdst, tg, __ATOMIC_RELAXED, __HIP_MEMORY_SCOPE_AGENT);
        }
      }

      // next-layer outputs — consumed only by later launches; off the critical path
      if (low) {
#pragma unroll
        for (int mt = 0; mt < 2; ++mt)
#pragma unroll
          for (int r = 0; r < 4; ++r) {
            const int m = mt * 16 + q * 4 + r;
            if (isFinal)
              outH[((size_t)m * T + t) * 512 + dir * 256 + ug] = hsv[mt][r];
            else
              Xnext[((size_t)(t >> 1) * 32 + m) * 1024 + (t & 1) * 512 + dir * 256 + ug] =
                  f2bf(hsv[mt][r]);
          }
      }
    }

    // persist c for the next chunk
    if (low) {
#pragma unroll
      for (int mt = 0; mt < 2; ++mt)
#pragma unroll
        for (int r = 0; r < 4; ++r)
          cb[(mt * 16 + q * 4 + r) * 256 + ug] = cst[mt][r];
    }
    if (wg == 0 && tid == 0)
      __hip_atomic_store(&doneL[dir * 16], doneVal, __ATOMIC_RELAXED,
                         __HIP_MEMORY_SCOPE_AGENT);
  } else {
    // ================= gemm role: chunk r+1 xz tiles =================
    const int gidx = (bid < 128) ? (grp * 7 + sub - 1) : (112 + (bid - 128));
    if (Cg > 0) {
      const int nM = Cg >> 2;          // Cg*32/128
      const int total = nM * 16;       // x 8 N-tiles x 2 dirs
      for (int tt = gidx; tt < total; tt += 240) {
        const int d = tt / (nM * 8);
        const int r2 = tt - d * (nM * 8);
        const int bn = r2 / nM;
        const int bm = r2 - bn * nM;
        gemm_tile(As, Bs, Af2, Ab2, WpK, biasL, xzW, Kg, Cg, bm, bn, d, tid);
      }
    }
    // ================= heater: hold clocks up until the chunk completes ========
    if (tid == 0) hdone = 0;
    __syncthreads();
    float hx = 1.0f + (float)tid * 1.0e-6f;
    const float ha = 1.0000001f, hc = 1.0e-7f;
    for (int it = 0; it < (1 << 16); ++it) {   // cap ~56ms: valve, never hangs
#pragma unroll 64
      for (int i = 0; i < 512; ++i)
        asm volatile("v_fmac_f32 %0, %1, %2" : "+v"(hx) : "v"(ha), "v"(hc));
      if (tid == 0) {
        int d0 = __hip_atomic_load(&doneL[0],  __ATOMIC_RELAXED, __HIP_MEMORY_SCOPE_AGENT);
        int d1 = __hip_atomic_load(&doneL[16], __ATOMIC_RELAXED, __HIP_MEMORY_SCOPE_AGENT);
        if (d0 >= doneVal && d1 >= doneVal) hdone = 1;
      }
      __syncthreads();
      if (hdone) break;
      __syncthreads();
    }
    if (hx == 1.2345e-37f) ((volatile float*)doneL)[8] = hx;  // never taken; keeps hx
  }
}

// ---------------- host ----------------
extern "C" void kernel_launch(void* const* d_in, const int* in_sizes, int n_in,
                              void* d_out, int out_size, void* d_ws, size_t ws_size,
                              hipStream_t stream) {
  char* ws = (char*)d_ws;
  constexpr size_t O_PET   = 0;                    // 3,473,408
  constexpr size_t O_WK    = 3473408;              // 14,680,064
  constexpr size_t O_BIAS  = O_WK + 14680064;      // 32,768
  constexpr size_t O_WR    = O_BIAS + 32768;       // 4,194,304
  constexpr size_t O_M0    = O_WR + 4194304;       // 54,272
  constexpr size_t O_M1    = O_M0 + 54272;         // 27,136
  constexpr size_t O_M2    = O_M1 + 27136;         // 13,568
  constexpr size_t O_M3    = O_M2 + 13568;         // 6,784
  constexpr size_t O_MODE  = O_M3 + 6784;          // 256
  constexpr size_t O_FLAGS = O_MODE + 256;         // 54,272 (4 layers x 3392 ints)
  constexpr size_t O_DONE  = O_FLAGS + 54272;      // 512 (4 layers x 32 ints)
  constexpr size_t O_HBUF  = O_DONE + 512;         // 262,144
  constexpr size_t O_CBUF  = O_HBUF + 262144;      // 262,144
  constexpr size_t O_XB0   = O_CBUF + 262144;      // 55,574,528
  constexpr size_t O_XB1   = O_XB0 + 55574528;     // 27,787,264
  constexpr size_t O_XC    = O_XB1 + 27787264;     // = 106,423,424

  int C = 0;
  if      (ws_size >= O_XC + 212ull * 589824) C = 212;
  else if (ws_size >= O_XC + 106ull * 589824) C = 106;
  else if (ws_size >= O_XC + 53ull * 589824)  C = 53;
  if (C == 0) { sentinelK<<<1, 64, 0, stream>>>((float*)d_out); return; }

  hipMemsetAsync(ws + O_FLAGS, 0, 54272 + 512 + 262144, stream);  // flags+done+hbuf

  modeK<<<1, 64, 0, stream>>>((const unsigned char*)d_in[1], (int*)(ws + O_MODE));
  maskK<<<212, 256, 0, stream>>>(d_in[1], (const int*)(ws + O_MODE),
                                 (unsigned char*)(ws + O_M0), (unsigned char*)(ws + O_M1),
                                 (unsigned char*)(ws + O_M2), (unsigned char*)(ws + O_M3),
                                 (float*)d_out + 3473408);
  petK<<<3392, 256, 0, stream>>>((float*)(ws + O_PET));

  u16* wk = (u16*)(ws + O_WK);
  u16* wrp = (u16*)(ws + O_WR);
  float* bias = (float*)(ws + O_BIAS);
  packW<<<2048, 256, 0, stream>>>((const float*)d_in[5],  wk + 0,       9, 1024);
  packW<<<2048, 256, 0, stream>>>((const float*)d_in[8],  wk + 524288,  9, 1024);
  packW<<<4096, 256, 0, stream>>>((const float*)d_in[11], wk + 1048576, 10, 1024);
  packW<<<4096, 256, 0, stream>>>((const float*)d_in[14], wk + 2097152, 10, 1024);
  packW<<<4096, 256, 0, stream>>>((const float*)d_in[17], wk + 3145728, 10, 1024);
  packW<<<4096, 256, 0, stream>>>((const float*)d_in[20], wk + 4194304, 10, 1024);
  packW<<<4096, 256, 0, stream>>>((const float*)d_in[23], wk + 5242880, 10, 1024);
  packW<<<4096, 256, 0, stream>>>((const float*)d_in[26], wk + 6291456, 10, 1024);
  packW<<<1024, 256, 0, stream>>>((const float*)d_in[6],  wrp + 0,       8, 1024);
  packW<<<1024, 256, 0, stream>>>((const float*)d_in[9],  wrp + 262144,  8, 1024);
  packW<<<1024, 256, 0, stream>>>((const float*)d_in[12], wrp + 524288,  8, 1024);
  packW<<<1024, 256, 0, stream>>>((const float*)d_in[15], wrp + 786432,  8, 1024);
  packW<<<1024, 256, 0, stream>>>((const float*)d_in[18], wrp + 1048576, 8, 1024);
  packW<<<1024, 256, 0, stream>>>((const float*)d_in[21], wrp + 1310720, 8, 1024);
  packW<<<1024, 256, 0, stream>>>((const float*)d_in[24], wrp + 1572864, 8, 1024);
  packW<<<1024, 256, 0, stream>>>((const float*)d_in[27], wrp + 1835008, 8, 1024);
  biasK<<<8, 256, 0, stream>>>((const float*)d_in[7],  (const float*)d_in[10], bias + 0);
  biasK<<<8, 256, 0, stream>>>((const float*)d_in[13], (const float*)d_in[16], bias + 2048);
  biasK<<<8, 256, 0, stream>>>((const float*)d_in[19], (const float*)d_in[22], bias + 4096);
  biasK<<<8, 256, 0, stream>>>((const float*)d_in[25], (const float*)d_in[28], bias + 6144);

  u16* XB0 = (u16*)(ws + O_XB0);
  u16* XB1 = (u16*)(ws + O_XB1);
  u16* xc  = (u16*)(ws + O_XC);
  float* xzp[2] = {(float*)(ws + O_XC + (size_t)C * 65536),
                   (float*)(ws + O_XC + (size_t)C * 65536 + (size_t)C * 262144)};
  int* flags = (int*)(ws + O_FLAGS);
  int* done  = (int*)(ws + O_DONE);
  u16* hbuf = (u16*)(ws + O_HBUF);
  float* cbuf = (float*)(ws + O_CBUF);
  unsigned char* masks[4] = {
      (unsigned char*)(ws + O_M0), (unsigned char*)(ws + O_M1),
      (unsigned char*)(ws + O_M2), (unsigned char*)(ws + O_M3)};

  const int    Ts[4]    = {1696, 848, 424, 212};
  const int    Ks[4]    = {512, 1024, 1024, 1024};
  const size_t wkOff[4] = {0, 1048576, 3145728, 5242880};
  const size_t wrOff[4] = {0, 524288, 1048576, 1572864};
  const int    bOff[4]  = {0, 2048, 4096, 6144};
  u16* Xin[4]  = {nullptr, XB0, XB1, XB0};   // layer2 out overlays XB0 (dead by then)
  u16* Xout[4] = {XB0, XB1, XB0, nullptr};

  for (int l = 0; l < 4; ++l) {
    const int T = Ts[l], K = Ks[l];
    const int Cl = (C < T) ? C : T;
    const int R = T / Cl;

    // chunk 0 inputs + xz
    const u16 *Af, *Ab;
    if (l == 0) {
      x0cK<<<2 * Cl, 256, 0, stream>>>((const float*)d_in[0], (const float*)d_in[3],
                                       (const float*)d_in[4], (const float*)d_in[2],
                                       (const float*)(ws + O_PET), xc, 0, T - Cl, Cl);
      Af = xc; Ab = xc + (size_t)Cl * 16384;
    } else {
      Af = Xin[l]; Ab = Xin[l] + (size_t)(T - Cl) * 32768;
    }
    gemmK<<<dim3(Cl / 4, 8, 2), 256, 0, stream>>>(
        Af, Ab, wk + wkOff[l], bias + bOff[l], xzp[0], K, Cl);

    for (int r = 0; r < R; ++r) {
      const int hasN = (r + 1 < R);
      const u16 *Af2 = nullptr, *Ab2 = nullptr;
      if (hasN) {
        if (l == 0) {
          x0cK<<<2 * Cl, 256, 0, stream>>>((const float*)d_in[0], (const float*)d_in[3],
                                           (const float*)d_in[4], (const float*)d_in[2],
                                           (const float*)(ws + O_PET), xc,
                                           (r + 1) * Cl, T - (r + 2) * Cl, Cl);
          Af2 = xc; Ab2 = xc + (size_t)Cl * 16384;
        } else {
          Af2 = Xin[l] + (size_t)(r + 1) * Cl * 32768;
          Ab2 = Xin[l] + (size_t)(T - (r + 2) * Cl) * 32768;
        }
      }
      fusedK<<<256, 256, 0, stream>>>(
          xzp[r & 1], wrp + wrOff[l], hbuf + (size_t)l * 32768,
          cbuf + (size_t)l * 16384, flags + (size_t)l * 3392, masks[l], Xout[l],
          (l == 3) ? (float*)d_out : nullptr, T, Cl, r * Cl, (l == 3) ? 1 : 0,
          Af2, Ab2, wk + wkOff[l], bias + bOff[l], xzp[(r + 1) & 1], K,
          hasN ? Cl : 0, done + (size_t)l * 32, r + 1, r * 16);
    }
  }
}

// Round 3
// 12824.847 us; speedup vs baseline: 36.5741x; 36.5741x over previous
//
#include <hip/hip_runtime.h>

typedef unsigned int u32;
typedef unsigned short u16;
typedef unsigned long long u64;
typedef __attribute__((ext_vector_type(8))) short bf16x8;
typedef __attribute__((ext_vector_type(4))) float f32x4;
typedef __attribute__((ext_vector_type(4))) unsigned int u32x4;

#define MFMA16(a, b, c) __builtin_amdgcn_mfma_f32_16x16x32_bf16((a), (b), (c), 0, 0, 0)

__device__ __forceinline__ float bf2f(u16 h) {
  union { u32 u; float f; } x; x.u = ((u32)h) << 16; return x.f;
}
__device__ __forceinline__ u16 f2bf(float f) {
  union { float f; u32 u; } x; x.f = f;
  u32 r = (x.u + 0x7FFFu + ((x.u >> 16) & 1u)) >> 16;
  return (u16)r;
}
__device__ __forceinline__ float sigm(float x) { return 1.0f / (1.0f + __expf(-x)); }
__device__ __forceinline__ float tanh_(float x) {
  float e = __expf(2.0f * x);
  return 1.0f - 2.0f / (e + 1.0f);   // safe at +/-inf
}

// Mechanism proven by r2 run: same-XCD plain stores land in the shared L2 and
// any L1-COLD load reads them fresh. L1-hot lines serve stale data (sc0 does
// NOT bypass L1 on gfx950). So: data + flags must only ever be read through
// addresses that are provably L1-cold (buffer/ring rotation); the agent-scope
// atomic path (LLC coherence point) remains the correctness/liveness backstop.
__device__ __forceinline__ bool flags8_plain(const u32* p, u32 tag) {
  u32x4 a, b;
  asm volatile("global_load_dwordx4 %0, %2, off\n\t"
               "global_load_dwordx4 %1, %2, off offset:16\n\t"
               "s_waitcnt vmcnt(0)"
               : "=&v"(a), "=&v"(b) : "v"(p) : "memory");
  return (a.x == tag) & (a.y == tag) & (a.z == tag) & (a.w == tag) &
         (b.x == tag) & (b.y == tag) & (b.z == tag) & (b.w == tag);
}
__device__ __forceinline__ bool flags8_agent(const u32* p, u32 tag) {
  const u64 want = (u64)tag * 0x0000000100000001ULL;
  bool ok = true;
#pragma unroll
  for (int i = 0; i < 4; ++i)
    ok &= (__hip_atomic_load((const u64*)p + i, __ATOMIC_RELAXED,
                             __HIP_MEMORY_SCOPE_AGENT) == want);
  return ok;
}
__device__ __forceinline__ u32x4 ld16_agent(const u32* p) {
  u64 a = __hip_atomic_load((const u64*)p, __ATOMIC_RELAXED, __HIP_MEMORY_SCOPE_AGENT);
  u64 b = __hip_atomic_load((const u64*)(p + 2), __ATOMIC_RELAXED, __HIP_MEMORY_SCOPE_AGENT);
  return (u32x4){(u32)a, (u32)(a >> 32), (u32)b, (u32)(b >> 32)};
}

__global__ void sentinelK(float* __restrict__ out) {
  if (threadIdx.x == 0) out[0] = 1.0e6f;   // "workspace too small" marker
}

// ---------------- mask dtype sniffing + pooled masks ----------------
__global__ void modeK(const unsigned char* __restrict__ m, int* __restrict__ mode) {
  if (threadIdx.x == 0) *mode = (m[1] | m[2]) ? 1 : 4;  // 1 = bool bytes, 4 = int32
}

__device__ __forceinline__ bool rawmask(const void* mp, int md, int b, int t) {
  if (md == 1) return ((const unsigned char*)mp)[b * 1696 + t] != 0;
  return ((const int*)mp)[b * 1696 + t] != 0;
}

__global__ __launch_bounds__(256) void maskK(
    const void* __restrict__ m, const int* __restrict__ mode,
    unsigned char* __restrict__ m0, unsigned char* __restrict__ m1,
    unsigned char* __restrict__ m2, unsigned char* __restrict__ m3,
    float* __restrict__ outMask) {
  int idx = blockIdx.x * 256 + threadIdx.x;  // 54272
  int t = idx >> 5, b = idx & 31;
  int md = *mode;
  m0[t * 32 + b] = rawmask(m, md, b, t) ? 1 : 0;
  if (t < 848) {
    bool a = rawmask(m, md, b, 2 * t) && rawmask(m, md, b, 2 * t + 1);
    m1[t * 32 + b] = a ? 1 : 0;
  }
  if (t < 424) {
    bool a = true;
    for (int j = 0; j < 4; ++j) a = a && rawmask(m, md, b, 4 * t + j);
    m2[t * 32 + b] = a ? 1 : 0;
  }
  if (t < 212) {
    bool a = true;
    for (int j = 0; j < 8; ++j) a = a && rawmask(m, md, b, 8 * t + j);
    m3[t * 32 + b] = a ? 1 : 0;
    outMask[b * 212 + t] = a ? 1.0f : 0.0f;
  }
}

// ---------------- positional encoding table (double, matches np.float64 ref) ----
__global__ __launch_bounds__(256) void petK(float* __restrict__ pet) {
  int idx = blockIdx.x * 256 + threadIdx.x;  // 1696*512
  int t = idx >> 9, d = idx & 511;
  double e = (double)((d >> 1) * 2) / 512.0;
  double freq = exp(e * -9.210340371976184);  // 10000^-e
  double ang = (double)t * freq;
  double vv = (d & 1) ? cos(ang) : sin(ang);
  pet[idx] = (float)vv;
}

// ---------------- weight packing: (K,N) fp32 -> (N,K) bf16 ----------------
__global__ __launch_bounds__(256) void packW(const float* __restrict__ src,
                                             u16* __restrict__ dst, int ksh, int N) {
  int idx = blockIdx.x * 256 + threadIdx.x;  // over N*K
  int n = idx >> ksh;
  int k = idx & ((1 << ksh) - 1);
  dst[idx] = f2bf(src[(size_t)k * N + n]);
}

__global__ void biasK(const float* __restrict__ fb, const float* __restrict__ bb,
                      float* __restrict__ dst) {
  int i = blockIdx.x * 256 + threadIdx.x;  // 2048
  dst[i] = (i < 1024) ? fb[i] : bb[i - 1024];
}

// ---------------- chunked mel projection + scale + pet -> xc [2][Cl][32][512] bf16 --
__global__ __launch_bounds__(256) void x0cK(
    const float* __restrict__ inp, const float* __restrict__ dw,
    const float* __restrict__ db, const float* __restrict__ scale,
    const float* __restrict__ pet, u16* __restrict__ xc,
    int t0f, int t0b, int Cl) {
  const int bid = blockIdx.x;          // 2*Cl
  const int d = (bid >= Cl) ? 1 : 0;
  const int lt = bid - d * Cl;
  const int t = (d ? t0b : t0f) + lt;
  __shared__ float xin[32][40];
  for (int i = threadIdx.x; i < 1280; i += 256) {
    int b = i / 40, k = i - b * 40;
    xin[b][k] = inp[((size_t)b * 1696 + t) * 40 + k];
  }
  __syncthreads();
  const float sc = 71.554175279993267f * scale[0];
  for (int dd = threadIdx.x; dd < 512; dd += 256) {
    float w[40];
#pragma unroll
    for (int k = 0; k < 40; ++k) w[k] = dw[k * 512 + dd];
    const float pv = pet[t * 512 + dd];
    const float bv = db[dd];
    u16* out = xc + (((size_t)d * Cl + lt) * 32) * 512 + dd;
    for (int b = 0; b < 32; ++b) {
      float acc = bv;
#pragma unroll
      for (int k = 0; k < 40; ++k) acc += xin[b][k] * w[k];
      out[(size_t)b * 512] = f2bf(acc * sc + pv);
    }
  }
}

// ---------------- one 128x128 GEMM tile (m97-style), used by gemmK and fusedK ------
__device__ __forceinline__ void gemm_tile(
    u16* As, u16* Bs,
    const u16* Af, const u16* Ab, const u16* Wp, const float* bias,
    float* out, int K, int Cl, int bm, int bn, int d, int tid) {
  const u16* A = (d ? Ab : Af) + (size_t)bm * 128 * K;
  const u16* W = Wp + (size_t)d * (size_t)K * 1024 + (size_t)bn * 128 * K;
  const int wv = tid >> 6, L = tid & 63, ln = L & 15, q = L >> 4;
  const int wm = wv & 1, wn = wv >> 1;
  const int srow = L >> 3, scol = (L & 7) * 8;

  f32x4 acc[4][4];
#pragma unroll
  for (int mt = 0; mt < 4; ++mt)
#pragma unroll
    for (int nt = 0; nt < 4; ++nt) acc[mt][nt] = (f32x4){0.f, 0.f, 0.f, 0.f};

  for (int kt = 0; kt < K; kt += 64) {
#pragma unroll
    for (int j = 0; j < 4; ++j) {
      const int rg = (j * 4 + wv) * 8;
      const u16* gA = A + (size_t)(rg + srow) * K + kt + scol;
      const u16* gB = W + (size_t)(rg + srow) * K + kt + scol;
      __builtin_amdgcn_global_load_lds(
          (const __attribute__((address_space(1))) void*)gA,
          (__attribute__((address_space(3))) void*)&As[rg * 64], 16, 0, 0);
      __builtin_amdgcn_global_load_lds(
          (const __attribute__((address_space(1))) void*)gB,
          (__attribute__((address_space(3))) void*)&Bs[rg * 64], 16, 0, 0);
    }
    __syncthreads();
#pragma unroll
    for (int ks = 0; ks < 2; ++ks) {
      bf16x8 a[4], b[4];
#pragma unroll
      for (int mt = 0; mt < 4; ++mt)
        a[mt] = *(const bf16x8*)&As[(wm * 64 + mt * 16 + ln) * 64 + ks * 32 + q * 8];
#pragma unroll
      for (int nt = 0; nt < 4; ++nt)
        b[nt] = *(const bf16x8*)&Bs[(wn * 64 + nt * 16 + ln) * 64 + ks * 32 + q * 8];
#pragma unroll
      for (int mt = 0; mt < 4; ++mt)
#pragma unroll
        for (int nt = 0; nt < 4; ++nt) acc[mt][nt] = MFMA16(a[mt], b[nt], acc[mt][nt]);
    }
    __syncthreads();
  }

  float* outd = out + (size_t)d * Cl * 32768;
#pragma unroll
  for (int nt = 0; nt < 4; ++nt) {
    const int col = bn * 128 + wn * 64 + nt * 16 + ln;
    const float bv = bias[d * 1024 + col];
#pragma unroll
    for (int mt = 0; mt < 4; ++mt) {
      const int row0 = bm * 128 + wm * 64 + mt * 16 + q * 4;
#pragma unroll
      for (int r = 0; r < 4; ++r)
        outd[(size_t)(row0 + r) * 1024 + col] = acc[mt][nt][r] + bv;
    }
  }
}

// ---------------- standalone xz GEMM for chunk 0 of each layer ----------------
__global__ __launch_bounds__(256) void gemmK(
    const u16* __restrict__ Af, const u16* __restrict__ Ab,
    const u16* __restrict__ Wp, const float* __restrict__ bias,
    float* __restrict__ out, int K, int Cl) {
  __shared__ u16 As[128 * 64];
  __shared__ u16 Bs[128 * 64];
  gemm_tile(As, Bs, Af, Ab, Wp, bias, out, K, Cl,
            blockIdx.x, blockIdx.y, blockIdx.z, threadIdx.x);
}

// ---------------- fused: recurrence + next-chunk GEMM + heater ----------------
// Sync role on bids {0,8,...,120}; rendezvous (proven real by r2) gates the fast
// path. Fast path: h via plain stores / plain loads on a 4-deep rotating buffer
// (L1-cold by rotation => fresh shared-L2 reads); flags via 8 mirror cache lines
// per step in a 32-step rotating ring (first touch is L1-cold => fresh L2 read).
// Agent-scope atomics remain: (a) the base-ring tag store every step, (b) the
// fallback poll if the cold mirrors miss, (c) the whole path when fastp=false.
// Tags are launch-unique (tagBase = launchIdx*256 + step) so no region clearing
// between launches/layers is needed and stale values can never false-positive.
__global__ __launch_bounds__(256) void fusedK(
    const float* __restrict__ xzR,    // [2][Cl][32][1024] f32, chunk r
    const u16* __restrict__ WrP,      // [2][1024][256] bf16 (n,k)
    u16* __restrict__ hbufS,          // shared: [2 dir][4 buf][32][256] bf16
    float* __restrict__ cbufL,        // per-layer: [2 dir][32][256] f32
    int* __restrict__ flagsS,         // shared: base ring + chk + mirror ring
    const unsigned char* __restrict__ msk,  // [T][32]
    u16* __restrict__ Xnext,          // [T/2][32][1024] bf16 (non-final)
    float* __restrict__ outH,         // [32][T][512] f32 (final)
    int T, int Cl, int s0, int isFinal,
    const u16* __restrict__ Af2, const u16* __restrict__ Ab2,
    const u16* __restrict__ WpK, const float* __restrict__ biasL,
    float* __restrict__ xzW, int Kg, int Cg,
    int* __restrict__ doneL, int doneVal, int tagBase) {
  __shared__ u16 As[128 * 64];
  __shared__ u16 Bs[128 * 64];
  __shared__ u16 A_lds[32 * 264];
  __shared__ int hdone;
  __shared__ int sh_fasti;
  const int bid = blockIdx.x;
  const int tid = threadIdx.x;
  const int sub = bid & 7;
  const int grp = bid >> 3;           // 0..31

  if (sub == 0 && grp < 16) {
    // ================= sync role: rid 0..15 =========
    const int rid = grp;
    const int dir = rid >> 3;
    const int wg = rid & 7;
    const int v = tid >> 6;
    const int L = tid & 63;
    const int ln = L & 15;
    const int q = L >> 4;
    const bool low = (L & 8) == 0;
    const int ug = wg * 32 + v * 8 + (L & 7);

    u32* ringB = (u32*)flagsS + dir * 128;          // [16 slot][8 wg] agent tags
    u32* ringM = (u32*)flagsS + 1024 + dir * 4096;  // [32 slot][8 line][16 u32]

    // --- placement rendezvous (once per launch, per dir; chk zeroed by host) ---
    if (tid == 0) {
      u32 xcc = (u32)__builtin_amdgcn_s_getreg(63508) & 0xFu;  // HW_REG_XCC_ID
      int* chk = flagsS + 256 + ((tagBase >> 8) << 2);         // [or0,or1,ct0,ct1]
      __hip_atomic_fetch_or(&chk[dir], (int)(1u << xcc), __ATOMIC_RELAXED,
                            __HIP_MEMORY_SCOPE_AGENT);
      __hip_atomic_fetch_add(&chk[2 + dir], 1, __ATOMIC_RELAXED,
                             __HIP_MEMORY_SCOPE_AGENT);
      int spins = 0;
      while (__hip_atomic_load(&chk[2 + dir], __ATOMIC_RELAXED,
                               __HIP_MEMORY_SCOPE_AGENT) < 8) {
        __builtin_amdgcn_s_sleep(2);
        if (++spins > (1 << 20)) {   // poison -> everyone takes the slow path
          __hip_atomic_fetch_or(&chk[dir], 0x7FFFFFFF, __ATOMIC_RELAXED,
                                __HIP_MEMORY_SCOPE_AGENT);
          break;
        }
      }
      int om = __hip_atomic_load(&chk[dir], __ATOMIC_RELAXED,
                                 __HIP_MEMORY_SCOPE_AGENT);
      sh_fasti = (__popc((u32)om) == 1) ? 1 : 0;
    }
    __syncthreads();
    const bool fastp = (sh_fasti != 0);

    bf16x8 bfr[2][8];
    {
      const u16* wr = WrP + (size_t)dir * 262144;
#pragma unroll
      for (int nt = 0; nt < 2; ++nt) {
        const int n = (nt * 2 + (ln >> 3)) * 256 + ug;  // gate-major column
#pragma unroll
        for (int ks = 0; ks < 8; ++ks)
          bfr[nt][ks] = *(const bf16x8*)(wr + (size_t)n * 256 + ks * 32 + q * 8);
      }
    }
    u16* hb = hbufS + dir * 32768;    // 4 buffers x 8192 u16
    float* cb = cbufL + dir * 8192;

    float cst[2][4];
    if (s0 == 0) {
#pragma unroll
      for (int mt = 0; mt < 2; ++mt)
#pragma unroll
        for (int r = 0; r < 4; ++r) cst[mt][r] = 0.f;
    } else {
#pragma unroll
      for (int mt = 0; mt < 2; ++mt)
#pragma unroll
        for (int r = 0; r < 4; ++r)
          cst[mt][r] = cb[(mt * 16 + q * 4 + r) * 256 + ug];
    }

    for (int s = s0; s < s0 + Cl; ++s) {
      const int t = dir ? (T - 1 - s) : s;
      const int lt = dir ? (s0 + Cl - 1 - s) : (s - s0);
      const int ls = s - s0;

      // prefetch xz + mask — loads in flight during the poll
      float xzv[2][2][4];
      const float* xzt = xzR + ((size_t)dir * Cl + lt) * 32768;
#pragma unroll
      for (int nt = 0; nt < 2; ++nt) {
        const int ncol = (nt * 2 + (ln >> 3)) * 256 + ug;
#pragma unroll
        for (int mt = 0; mt < 2; ++mt)
#pragma unroll
          for (int r = 0; r < 4; ++r)
            xzv[mt][nt][r] = xzt[(size_t)(mt * 16 + q * 4 + r) * 1024 + ncol];
      }
      const u32 mk0 = *(const u32*)&msk[t * 32 + q * 4];
      const u32 mk1 = *(const u32*)&msk[t * 32 + 16 + q * 4];

      // poll previous step's 8 producer tags (skip at chunk start: stream order
      // guarantees the previous launch's h/c are visible — baseline-proven)
      if (ls > 0) {
        if (tid == 0) {
          const u32 tg = (u32)(tagBase + ls);              // tag of step ls-1
          const u32* fb = ringB + ((ls - 1) & 15) * 8;
          bool got = false;
          if (fastp) {
            const u32* fm = ringM + ((ls - 1) & 31) * 128;
            for (int j = 0; j < 8; ++j) {                  // 8 L1-cold L2 reads
              if (flags8_plain(fm + j * 16, tg)) { got = true; break; }
            }
          }
          if (!got) {                                      // proven agent poll
            int spins = 0;
            while (!flags8_agent(fb, tg)) {
              __builtin_amdgcn_s_sleep(1);
              if (++spins > (1 << 21)) break;              // valve: never hang
            }
          }
        }
        __syncthreads();
      }

      // stage h(s-1) (buffer (s-1)&3) into LDS — linear, 16B/lane coalesced.
      // fast: plain loads (L1-cold by 4-deep rotation => fresh shared L2)
      {
        const u32* hsrc = (const u32*)(hb + ((s + 3) & 3) * 8192);
        const int m0 = tid >> 5;
        const int c4 = (tid & 31) * 4;     // u32 col base
        const u32* p0 = hsrc + (m0)*128 + c4;
        const u32* p1 = hsrc + (8 + m0) * 128 + c4;
        const u32* p2 = hsrc + (16 + m0) * 128 + c4;
        const u32* p3 = hsrc + (24 + m0) * 128 + c4;
        u32x4 v0, v1, v2, v3;
        if (fastp) {
          v0 = *(const u32x4*)p0; v1 = *(const u32x4*)p1;
          v2 = *(const u32x4*)p2; v3 = *(const u32x4*)p3;
        } else {
          v0 = ld16_agent(p0); v1 = ld16_agent(p1);
          v2 = ld16_agent(p2); v3 = ld16_agent(p3);
        }
        const int lb = (tid & 31) * 8;     // u16 col base
        *(u32x4*)&A_lds[(m0)*264 + lb] = v0;
        *(u32x4*)&A_lds[(8 + m0) * 264 + lb] = v1;
        *(u32x4*)&A_lds[(16 + m0) * 264 + lb] = v2;
        *(u32x4*)&A_lds[(24 + m0) * 264 + lb] = v3;
      }
      __syncthreads();

      f32x4 acc[2][2];
#pragma unroll
      for (int mt = 0; mt < 2; ++mt)
#pragma unroll
        for (int nt = 0; nt < 2; ++nt) acc[mt][nt] = (f32x4){0.f, 0.f, 0.f, 0.f};
#pragma unroll
      for (int ks = 0; ks < 8; ++ks) {
        bf16x8 a0 = *(const bf16x8*)&A_lds[ln * 264 + ks * 32 + q * 8];
        bf16x8 a1 = *(const bf16x8*)&A_lds[(16 + ln) * 264 + ks * 32 + q * 8];
        acc[0][0] = MFMA16(a0, bfr[0][ks], acc[0][0]);
        acc[0][1] = MFMA16(a0, bfr[1][ks], acc[0][1]);
        acc[1][0] = MFMA16(a1, bfr[0][ks], acc[1][0]);
        acc[1][1] = MFMA16(a1, bfr[1][ks], acc[1][1]);
      }

      float hsv[2][4];
#pragma unroll
      for (int mt = 0; mt < 2; ++mt) {
        const u32 mkw = mt ? mk1 : mk0;
#pragma unroll
        for (int r = 0; r < 4; ++r) {
          float z0 = acc[mt][0][r] + xzv[mt][0][r];  // i (low half) / f (high half)
          float z1 = acc[mt][1][r] + xzv[mt][1][r];  // g / o
          float z0p = __shfl_xor(z0, 8);
          float z1p = __shfl_xor(z1, 8);
          float iv = low ? z0 : z0p;
          float fv = low ? z0p : z0;
          float gv = low ? z1 : z1p;
          float ov = low ? z1p : z1;
          float cold = cst[mt][r];
          float cn = sigm(fv) * cold + sigm(iv) * tanh_(gv);
          float hn = sigm(ov) * tanh_(cn);
          const int m = mt * 16 + q * 4 + r;
          float hold = bf2f(A_lds[m * 264 + ug]);
          bool mb = ((mkw >> (8 * r)) & 0xffu) != 0;
          cst[mt][r] = mb ? cn : cold;
          float hs = mb ? hn : hold;
          hsv[mt][r] = hs;
        }
      }

      // publish h(s) to buffer s&3: fast = plain stores into the shared L2,
      // slow = relaxed agent atomics to the coherence point
      {
        u32* hdst = (u32*)(hb + (s & 3) * 8192);
#pragma unroll
        for (int mt = 0; mt < 2; ++mt) {
#pragma unroll
          for (int r = 0; r < 4; ++r) {
            u32 lo = (u32)f2bf(hsv[mt][r]);
            u32 par = (u32)__shfl_xor((int)lo, 1);
            u32 val = lo | (par << 16);
            if (low && ((ln & 1) == 0)) {
              const int m = mt * 16 + q * 4 + r;
              if (fastp)
                hdst[m * 128 + (ug >> 1)] = val;
              else
                __hip_atomic_store(&hdst[m * 128 + (ug >> 1)], val,
                                   __ATOMIC_RELAXED, __HIP_MEMORY_SCOPE_AGENT);
            }
          }
        }
      }

      asm volatile("s_waitcnt vmcnt(0)" ::: "memory");  // this wave's h at L2
      __syncthreads();                                   // all waves drained
      if (tid == 0) {
        const u32 tg = (u32)(tagBase + ls + 1);
        if (fastp) {
          u32* mir = ringM + (ls & 31) * 128 + wg;       // 8 mirror lines
#pragma unroll
          for (int j = 0; j < 8; ++j)
            asm volatile("global_store_dword %0, %1, off" ::"v"(mir + j * 16),
                         "v"(tg) : "memory");
        }
        __hip_atomic_store(ringB + (ls & 15) * 8 + wg, tg, __ATOMIC_RELAXED,
                           __HIP_MEMORY_SCOPE_AGENT);    // backstop + slow path
      }

      // next-layer outputs — consumed only by later launches; off the critical path
      if (low) {
#pragma unroll
        for (int mt = 0; mt < 2; ++mt)
#pragma unroll
          for (int r = 0; r < 4; ++r) {
            const int m = mt * 16 + q * 4 + r;
            if (isFinal)
              outH[((size_t)m * T + t) * 512 + dir * 256 + ug] = hsv[mt][r];
            else
              Xnext[((size_t)(t >> 1) * 32 + m) * 1024 + (t & 1) * 512 + dir * 256 + ug] =
                  f2bf(hsv[mt][r]);
          }
      }
    }

    // persist c for the next chunk
    if (low) {
#pragma unroll
      for (int mt = 0; mt < 2; ++mt)
#pragma unroll
        for (int r = 0; r < 4; ++r)
          cb[(mt * 16 + q * 4 + r) * 256 + ug] = cst[mt][r];
    }
    if (wg == 0 && tid == 0)
      __hip_atomic_store(&doneL[dir * 16], doneVal, __ATOMIC_RELAXED,
                         __HIP_MEMORY_SCOPE_AGENT);
  } else {
    // ================= gemm role: chunk r+1 xz tiles =================
    const int gidx = (bid < 128) ? (grp * 7 + sub - 1) : (112 + (bid - 128));
    if (Cg > 0) {
      const int nM = Cg >> 2;          // Cg*32/128
      const int total = nM * 16;       // x 8 N-tiles x 2 dirs
      for (int tt = gidx; tt < total; tt += 240) {
        const int d = tt / (nM * 8);
        const int r2 = tt - d * (nM * 8);
        const int bn = r2 / nM;
        const int bm = r2 - bn * nM;
        gemm_tile(As, Bs, Af2, Ab2, WpK, biasL, xzW, Kg, Cg, bm, bn, d, tid);
      }
    }
    // ================= heater: hold clocks up until the chunk completes ========
    if (tid == 0) hdone = 0;
    __syncthreads();
    float hx = 1.0f + (float)tid * 1.0e-6f;
    const float ha = 1.0000001f, hc = 1.0e-7f;
    for (int it = 0; it < (1 << 16); ++it) {   // cap: valve, never hangs
#pragma unroll 64
      for (int i = 0; i < 512; ++i)
        asm volatile("v_fmac_f32 %0, %1, %2" : "+v"(hx) : "v"(ha), "v"(hc));
      if (tid == 0) {
        int d0 = __hip_atomic_load(&doneL[0],  __ATOMIC_RELAXED, __HIP_MEMORY_SCOPE_AGENT);
        int d1 = __hip_atomic_load(&doneL[16], __ATOMIC_RELAXED, __HIP_MEMORY_SCOPE_AGENT);
        if (d0 >= doneVal && d1 >= doneVal) hdone = 1;
      }
      __syncthreads();
      if (hdone) break;
      __syncthreads();
    }
    if (hx == 1.2345e-37f) ((volatile float*)doneL)[8] = hx;  // never taken; keeps hx
  }
}

// ---------------- host ----------------
extern "C" void kernel_launch(void* const* d_in, const int* in_sizes, int n_in,
                              void* d_out, int out_size, void* d_ws, size_t ws_size,
                              hipStream_t stream) {
  char* ws = (char*)d_ws;
  constexpr size_t O_PET   = 0;                    // 3,473,408
  constexpr size_t O_WK    = 3473408;              // 14,680,064
  constexpr size_t O_BIAS  = O_WK + 14680064;      // 32,768
  constexpr size_t O_WR    = O_BIAS + 32768;       // 4,194,304
  constexpr size_t O_M0    = O_WR + 4194304;       // 54,272
  constexpr size_t O_M1    = O_M0 + 54272;         // 27,136
  constexpr size_t O_M2    = O_M1 + 27136;         // 13,568
  constexpr size_t O_M3    = O_M2 + 13568;         // 6,784
  constexpr size_t O_MODE  = O_M3 + 6784;          // 256
  constexpr size_t O_FLAGS = O_MODE + 256;         // 54,272 (rings + chk + mirrors)
  constexpr size_t O_DONE  = O_FLAGS + 54272;      // 512 (4 layers x 32 ints)
  constexpr size_t O_HBUF  = O_DONE + 512;         // 262,144 (131,072 used: shared h)
  constexpr size_t O_CBUF  = O_HBUF + 262144;      // 262,144
  constexpr size_t O_XB0   = O_CBUF + 262144;      // 55,574,528
  constexpr size_t O_XB1   = O_XB0 + 55574528;     // 27,787,264
  constexpr size_t O_XC    = O_XB1 + 27787264;     // = 106,423,424

  int C = 0;
  if      (ws_size >= O_XC + 212ull * 589824) C = 212;
  else if (ws_size >= O_XC + 106ull * 589824) C = 106;
  else if (ws_size >= O_XC + 53ull * 589824)  C = 53;
  if (C == 0) { sentinelK<<<1, 64, 0, stream>>>((float*)d_out); return; }

  hipMemsetAsync(ws + O_FLAGS, 0, 54272 + 512 + 131072, stream);  // flags+done+hbuf

  modeK<<<1, 64, 0, stream>>>((const unsigned char*)d_in[1], (int*)(ws + O_MODE));
  maskK<<<212, 256, 0, stream>>>(d_in[1], (const int*)(ws + O_MODE),
                                 (unsigned char*)(ws + O_M0), (unsigned char*)(ws + O_M1),
                                 (unsigned char*)(ws + O_M2), (unsigned char*)(ws + O_M3),
                                 (float*)d_out + 3473408);
  petK<<<3392, 256, 0, stream>>>((float*)(ws + O_PET));

  u16* wk = (u16*)(ws + O_WK);
  u16* wrp = (u16*)(ws + O_WR);
  float* bias = (float*)(ws + O_BIAS);
  packW<<<2048, 256, 0, stream>>>((const float*)d_in[5],  wk + 0,       9, 1024);
  packW<<<2048, 256, 0, stream>>>((const float*)d_in[8],  wk + 524288,  9, 1024);
  packW<<<4096, 256, 0, stream>>>((const float*)d_in[11], wk + 1048576, 10, 1024);
  packW<<<4096, 256, 0, stream>>>((const float*)d_in[14], wk + 2097152, 10, 1024);
  packW<<<4096, 256, 0, stream>>>((const float*)d_in[17], wk + 3145728, 10, 1024);
  packW<<<4096, 256, 0, stream>>>((const float*)d_in[20], wk + 4194304, 10, 1024);
  packW<<<4096, 256, 0, stream>>>((const float*)d_in[23], wk + 5242880, 10, 1024);
  packW<<<4096, 256, 0, stream>>>((const float*)d_in[26], wk + 6291456, 10, 1024);
  packW<<<1024, 256, 0, stream>>>((const float*)d_in[6],  wrp + 0,       8, 1024);
  packW<<<1024, 256, 0, stream>>>((const float*)d_in[9],  wrp + 262144,  8, 1024);
  packW<<<1024, 256, 0, stream>>>((const float*)d_in[12], wrp + 524288,  8, 1024);
  packW<<<1024, 256, 0, stream>>>((const float*)d_in[15], wrp + 786432,  8, 1024);
  packW<<<1024, 256, 0, stream>>>((const float*)d_in[18], wrp + 1048576, 8, 1024);
  packW<<<1024, 256, 0, stream>>>((const float*)d_in[21], wrp + 1310720, 8, 1024);
  packW<<<1024, 256, 0, stream>>>((const float*)d_in[24], wrp + 1572864, 8, 1024);
  packW<<<1024, 256, 0, stream>>>((const float*)d_in[27], wrp + 1835008, 8, 1024);
  biasK<<<8, 256, 0, stream>>>((const float*)d_in[7],  (const float*)d_in[10], bias + 0);
  biasK<<<8, 256, 0, stream>>>((const float*)d_in[13], (const float*)d_in[16], bias + 2048);
  biasK<<<8, 256, 0, stream>>>((const float*)d_in[19], (const float*)d_in[22], bias + 4096);
  biasK<<<8, 256, 0, stream>>>((const float*)d_in[25], (const float*)d_in[28], bias + 6144);

  u16* XB0 = (u16*)(ws + O_XB0);
  u16* XB1 = (u16*)(ws + O_XB1);
  u16* xc  = (u16*)(ws + O_XC);
  float* xzp[2] = {(float*)(ws + O_XC + (size_t)C * 65536),
                   (float*)(ws + O_XC + (size_t)C * 65536 + (size_t)C * 262144)};
  int* flags = (int*)(ws + O_FLAGS);
  int* done  = (int*)(ws + O_DONE);
  u16* hbuf = (u16*)(ws + O_HBUF);
  float* cbuf = (float*)(ws + O_CBUF);
  unsigned char* masks[4] = {
      (unsigned char*)(ws + O_M0), (unsigned char*)(ws + O_M1),
      (unsigned char*)(ws + O_M2), (unsigned char*)(ws + O_M3)};

  const int    Ts[4]    = {1696, 848, 424, 212};
  const int    Ks[4]    = {512, 1024, 1024, 1024};
  const size_t wkOff[4] = {0, 1048576, 3145728, 5242880};
  const size_t wrOff[4] = {0, 524288, 1048576, 1572864};
  const int    bOff[4]  = {0, 2048, 4096, 6144};
  u16* Xin[4]  = {nullptr, XB0, XB1, XB0};   // layer2 out overlays XB0 (dead by then)
  u16* Xout[4] = {XB0, XB1, XB0, nullptr};

  int launchIdx = 0;
  for (int l = 0; l < 4; ++l) {
    const int T = Ts[l], K = Ks[l];
    const int Cl = (C < T) ? C : T;
    const int R = T / Cl;

    if (l > 0)  // h(-1)=0 for the new layer (shared h region; layers sequential)
      hipMemsetAsync(ws + O_HBUF, 0, 131072, stream);

    // chunk 0 inputs + xz
    const u16 *Af, *Ab;
    if (l == 0) {
      x0cK<<<2 * Cl, 256, 0, stream>>>((const float*)d_in[0], (const float*)d_in[3],
                                       (const float*)d_in[4], (const float*)d_in[2],
                                       (const float*)(ws + O_PET), xc, 0, T - Cl, Cl);
      Af = xc; Ab = xc + (size_t)Cl * 16384;
    } else {
      Af = Xin[l]; Ab = Xin[l] + (size_t)(T - Cl) * 32768;
    }
    gemmK<<<dim3(Cl / 4, 8, 2), 256, 0, stream>>>(
        Af, Ab, wk + wkOff[l], bias + bOff[l], xzp[0], K, Cl);

    for (int r = 0; r < R; ++r) {
      const int hasN = (r + 1 < R);
      const u16 *Af2 = nullptr, *Ab2 = nullptr;
      if (hasN) {
        if (l == 0) {
          x0cK<<<2 * Cl, 256, 0, stream>>>((const float*)d_in[0], (const float*)d_in[3],
                                           (const float*)d_in[4], (const float*)d_in[2],
                                           (const float*)(ws + O_PET), xc,
                                           (r + 1) * Cl, T - (r + 2) * Cl, Cl);
          Af2 = xc; Ab2 = xc + (size_t)Cl * 16384;
        } else {
          Af2 = Xin[l] + (size_t)(r + 1) * Cl * 32768;
          Ab2 = Xin[l] + (size_t)(T - (r + 2) * Cl) * 32768;
        }
      }
      fusedK<<<256, 256, 0, stream>>>(
          xzp[r & 1], wrp + wrOff[l], hbuf,
          cbuf + (size_t)l * 16384, flags, masks[l], Xout[l],
          (l == 3) ? (float*)d_out : nullptr, T, Cl, r * Cl, (l == 3) ? 1 : 0,
          Af2, Ab2, wk + wkOff[l], bias + bOff[l], xzp[(r + 1) & 1], K,
          hasN ? Cl : 0, done + (size_t)l * 32, r + 1, launchIdx << 8);
      ++launchIdx;
    }
  }
}